// Round 3
// baseline (113.300 us; speedup 1.0000x reference)
//
#include <hip/hip_runtime.h>

// Problem constants (from reference setup_inputs):
//   B=4096 (objects/rows), C=4096 (channels), M=64, S=64 -> M*S = 4096 slots.
// Algebraic collapse of the reference:
//   out[b,c] = count[b] * x[b,c], where
//   count[b] = #{(m,s) : assignments[m,s] == b}   (b >= 0, so -1 padding never matches)
//
// One dispatch. Each block owns R=4 consecutive rows:
//   1) single pass over the 16 KB assignments array (L2-resident), counting
//      matches for all 4 rows at once (scan traffic amortized 4x vs 1 row/block),
//      counts packed 2x16-bit -> butterfly reduce is 12 shuffles,
//   2) one LDS cross-wave combine,
//   3) pure streaming phase: 4 rows x 4 float4/thread, fully coalesced.

#define BLOCK 256
#define R 4                   // rows per block
#define C_VEC 1024            // 4096 floats / 4 per float4
#define KPT 4                 // float4 per thread per row (1024 / 256)
#define APT 4                 // int4 per thread over assignments (1024 / 256)

typedef float v4f __attribute__((ext_vector_type(4)));

__global__ __launch_bounds__(BLOCK) void mux_fused_kernel(
    const v4f* __restrict__ x,
    const int4* __restrict__ a4,
    v4f* __restrict__ out) {
    const int tid = threadIdx.x;
    const int r0 = blockIdx.x * R;

    // 1) one scan of assignments, counting matches for rows r0..r0+3.
    //    Pack counts as two 2x16-bit accumulators (max count 4096 < 65536).
    int p01 = 0, p23 = 0;
#pragma unroll
    for (int k = 0; k < APT; ++k) {
        int4 a = a4[tid + BLOCK * k];
#pragma unroll
        for (int c = 0; c < 4; ++c) {
            int av = (c == 0) ? a.x : (c == 1) ? a.y : (c == 2) ? a.z : a.w;
            int d = av - r0;
            p01 += (d == 0) + ((d == 1) << 16);
            p23 += (d == 2) + ((d == 3) << 16);
        }
    }

    // 2) butterfly reduce across the 64-lane wave (12 shuffles total)
#pragma unroll
    for (int off = 32; off > 0; off >>= 1) {
        p01 += __shfl_xor(p01, off, 64);
        p23 += __shfl_xor(p23, off, 64);
    }

    // cross-wave combine via LDS
    __shared__ int2 wsum[BLOCK / 64];
    const int wave = tid >> 6;
    if ((tid & 63) == 0) wsum[wave] = make_int2(p01, p23);
    __syncthreads();
    int t01 = 0, t23 = 0;
#pragma unroll
    for (int w = 0; w < BLOCK / 64; ++w) { t01 += wsum[w].x; t23 += wsum[w].y; }

    float s[R];
    s[0] = (float)(t01 & 0xFFFF);
    s[1] = (float)(t01 >> 16);
    s[2] = (float)(t23 & 0xFFFF);
    s[3] = (float)(t23 >> 16);

    // 3) stream 4 rows: load float4, scale, store (coalesced 4 KB per step)
#pragma unroll
    for (int j = 0; j < R; ++j) {
        const long base = (long)(r0 + j) * C_VEC;
        const float sj = s[j];
#pragma unroll
        for (int k = 0; k < KPT; ++k) {
            const long i = base + tid + BLOCK * k;
            v4f v = x[i];
            v *= sj;
            out[i] = v;
        }
    }
}

extern "C" void kernel_launch(void* const* d_in, const int* in_sizes, int n_in,
                              void* d_out, int out_size, void* d_ws, size_t ws_size,
                              hipStream_t stream) {
    const float* x = (const float*)d_in[0];
    const int* assignments = (const int*)d_in[1];
    float* out = (float*)d_out;

    const int B = 4096;  // rows; R per block
    mux_fused_kernel<<<dim3(B / R), dim3(BLOCK), 0, stream>>>(
        (const v4f*)x, (const int4*)assignments, (v4f*)out);
}